// Round 14
// baseline (9350.101 us; speedup 1.0000x reference)
//
#include <hip/hip_runtime.h>

// Problem constants (from reference)
#define SEQ   8192
#define HID   256
#define G3    768      // 3*HID
#define TSTART 1024    // SEQ/8
#define NEGD  1365     // SEQ/6
#define TCNT  5791     // (SEQ - 10 - NEGD - 4 + 2) - TSTART
#define DENOMF 23164.0f // TCNT*4

typedef _Float16 half8_t __attribute__((ext_vector_type(8)));
typedef float    f32x4  __attribute__((ext_vector_type(4)));

__device__ __forceinline__ float sigmoidf_fast(float x) {
  return 1.0f / (1.0f + __expf(-x));
}
// tanh via sigmoid form: safe at both extremes (exp under/overflow -> +-1)
__device__ __forceinline__ float tanhf_fast(float x) {
  return 2.0f / (1.0f + __expf(-2.0f * x)) - 1.0f;
}

// ---------------------------------------------------------------------------
// init: zero the loss accumulators (ws is poisoned 0xAA every call)
// ---------------------------------------------------------------------------
__global__ void init_kernel(float* accum) {
  if (threadIdx.x < 2) accum[threadIdx.x] = 0.0f;
}

// ---------------------------------------------------------------------------
// Phase A: xW = data @ Wih^T + bih -> f32 [SEQ][768]. All f32.
// grid (256, 3), block 256. Thread owns output col o; 32-row x-tile in LDS.
// ---------------------------------------------------------------------------
__global__ __launch_bounds__(256) void xw_kernel(
    const float* __restrict__ data, const float* __restrict__ Wih,
    const float* __restrict__ bih, float* __restrict__ xw)
{
  __shared__ float4 xs4[32 * 64];   // 32 rows x 256 f32 = 32 KB
  const int o  = blockIdx.y * 256 + threadIdx.x;
  const int m0 = blockIdx.x * 32;

  float* xsf = (float*)xs4;
  for (int r = 0; r < 32; ++r)
    xsf[r * 256 + threadIdx.x] = data[(size_t)(m0 + r) * 256 + threadIdx.x];
  __syncthreads();

  const float b = bih[o];
  float acc[32];
#pragma unroll
  for (int r = 0; r < 32; ++r) acc[r] = b;

  const float4* wrow = (const float4*)(Wih + (size_t)o * 256);
  for (int kc = 0; kc < 4; ++kc) {
    float4 w[16];
#pragma unroll
    for (int j = 0; j < 16; ++j) w[j] = wrow[kc * 16 + j];
#pragma unroll
    for (int r = 0; r < 32; ++r) {
      const float4* xr = xs4 + r * 64 + kc * 16;
      float a0 = 0.f, a1 = 0.f, a2 = 0.f, a3 = 0.f;
#pragma unroll
      for (int j = 0; j < 4; ++j) {
        float4 x0 = xr[4 * j + 0], x1 = xr[4 * j + 1];
        float4 x2 = xr[4 * j + 2], x3 = xr[4 * j + 3];
        float4 w0 = w[4 * j + 0], w1 = w[4 * j + 1];
        float4 w2 = w[4 * j + 2], w3 = w[4 * j + 3];
        a0 = fmaf(w0.x, x0.x, fmaf(w0.y, x0.y, fmaf(w0.z, x0.z, fmaf(w0.w, x0.w, a0))));
        a1 = fmaf(w1.x, x1.x, fmaf(w1.y, x1.y, fmaf(w1.z, x1.z, fmaf(w1.w, x1.w, a1))));
        a2 = fmaf(w2.x, x2.x, fmaf(w2.y, x2.y, fmaf(w2.z, x2.z, fmaf(w2.w, x2.w, a2))));
        a3 = fmaf(w3.x, x3.x, fmaf(w3.y, x3.y, fmaf(w3.z, x3.z, fmaf(w3.w, x3.w, a3))));
      }
      acc[r] += (a0 + a1) + (a2 + a3);
    }
  }
  for (int r = 0; r < 32; ++r)
    xw[(size_t)(m0 + r) * G3 + o] = acc[r];
}

// ---------------------------------------------------------------------------
// data row norms: one wave per row (f32 data)
// ---------------------------------------------------------------------------
__global__ __launch_bounds__(256) void rnorm_kernel(
    const float* __restrict__ data, float* __restrict__ rn)
{
  int wave = threadIdx.x >> 6, lane = threadIdx.x & 63;
  int row = blockIdx.x * 4 + wave;
  const float* xr = data + (size_t)row * HID;
  float a = xr[lane], b = xr[lane + 64], c = xr[lane + 128], d = xr[lane + 192];
  float s = a * a + b * b + c * c + d * d;
#pragma unroll
  for (int off = 32; off; off >>= 1) s += __shfl_xor(s, off, 64);
  if (lane == 0) rn[row] = fmaxf(sqrtf(s), 1e-8f);
}

// ---------------------------------------------------------------------------
// Phase B: sequential GRU scan via MFMA matvec. ONE block, 512 threads
// (8 waves, 2/SIMD) -- round-10 structure (7613us, passed) with the zout
// store MANUALLY ROTATED: step s stores row s-1, tucked between the bf
// ds_reads and the MFMAs; epilogue stores the final row.
//
// A/B history on store placement (pipe busy invariant at ~1526 cyc/SIMD
// = the 96-MFMA matvec issue floor in all three):
//   round 10: store just before __syncthreads          -> 2231 cyc/step
//   round 12: asm barrier + store at loop top           -> 2406 (+175)
//   round 13: __syncthreads + store at loop top         -> 2403 (+172)
// Conclusion: the asm barrier was innocent; the LOOP-TOP store position
// costs ~170 cyc -- its if(writer) exec-mask + address calc delays the
// latency-critical bf ds_read issue, and in-order vmcnt retirement queues
// the store ahead of the xw loads. This version keeps the store out of
// both the loop top AND the pre-barrier drain shadow: ds_reads issue
// first (startup unchanged), the store issues under the MFMA phase, and
// at the barrier every outstanding vmem op is ~1900 cyc old -> the
// __syncthreads vmcnt(0) drain waits on nothing. If round 10's drain was
// already free, this lands neutral and 2231 is the structure's plateau.
//
// Mappings (verified round 4): A-frag row = lane&15, k = kc*32+(lane>>4)*8+j.
// B = h broadcast into all 16 columns -> every C column equals y.
// C: col=lane&15, row=(lane>>4)*4+reg. Lane (g, jsel=lane&7) finalizes
// column cm = w*32+(jsel>>2)*16+g*4+(jsel&3); copy r16<8 publishes.
// ---------------------------------------------------------------------------
__global__ __launch_bounds__(512, 2) void gru_kernel(
    const float* __restrict__ Whh, const float* __restrict__ bhh,
    const float* __restrict__ xw, float* __restrict__ zout)
{
  __shared__ __align__(16) _Float16 hbuf[2][HID];   // double-buffered h
  const int i    = threadIdx.x;
  const int w    = i >> 6;
  const int lane = i & 63;
  const int g    = lane >> 4;          // C-rows g*4..g*4+3; B k-sub g*8..+8
  const int r16  = lane & 15;          // A-fragment row within a 16-row tile
  const int jsel = lane & 7;           // (t2,reg) this lane finalizes
  const int cm   = w * 32 + (jsel >> 2) * 16 + g * 4 + (jsel & 3);
  const bool writer = r16 < 8;         // one finalizer copy publishes

  // --- resident A-fragments: [G*2+t2][kc], 192 AGPR-backed regs ---
  half8_t A[6][8];
#pragma unroll
  for (int G = 0; G < 3; ++G)
#pragma unroll
    for (int t2 = 0; t2 < 2; ++t2) {
      const int row = G * 256 + w * 32 + t2 * 16 + r16;
      const float* wp = Whh + (size_t)row * 256 + g * 8;
#pragma unroll
      for (int kc = 0; kc < 8; ++kc) {
        const float4* w4 = (const float4*)(wp + kc * 32);
        float4 u = w4[0], v = w4[1];
        half8_t f;
        f[0] = (_Float16)u.x; f[1] = (_Float16)u.y;
        f[2] = (_Float16)u.z; f[3] = (_Float16)u.w;
        f[4] = (_Float16)v.x; f[5] = (_Float16)v.y;
        f[6] = (_Float16)v.z; f[7] = (_Float16)v.w;
        A[G * 2 + t2][kc] = f;
      }
    }

  const float br  = bhh[cm];
  const float bz  = bhh[256 + cm];
  const float bnn = bhh[512 + cm];

  if (i < HID) hbuf[0][i] = (_Float16)0.0f;
  __syncthreads();

  float hreg = 0.0f;   // h[cm], tracked by both r16-parity copies
  const float* xwp = xw;       // row-s pointer, += G3 per step
  float*       zps = zout;     // row-(s-1) store pointer (used when s>0)
  float xr0 = xwp[cm], xz0 = xwp[256 + cm], xn0 = xwp[512 + cm];

  const f32x4 zf = {0.f, 0.f, 0.f, 0.f};

  for (int s = 0; s < SEQ; ++s) {
    // next step's xW prefetch, unconditional (last iter reads into the rn
    // region: in-bounds garbage, never used)
    xwp += G3;
    float xr1 = xwp[cm], xz1 = xwp[256 + cm], xn1 = xwp[512 + cm];

    const _Float16* hc = hbuf[s & 1];

    // --- all 8 B-frags upfront (compile-time indexed; reads overlap) ---
    half8_t bf[8];
#pragma unroll
    for (int kc = 0; kc < 8; ++kc)
      bf[kc] = *(const half8_t*)(hc + kc * 32 + g * 8);

    // --- rotated zout store: row s-1 (hreg still holds h_{s-1}) issues
    //     here, under the MFMA phase; ack completes long before the next
    //     barrier so the __syncthreads vmcnt(0) drain waits on nothing ---
    if (s && writer) {
      zps[cm] = hreg;
      zps += HID;
    }

    // --- r,z tiles first: 32 MFMAs, 4 independent chains ---
    f32x4 acc[6];
#pragma unroll
    for (int t = 0; t < 4; ++t)
      acc[t] = __builtin_amdgcn_mfma_f32_16x16x32_f16(A[t][0], bf[0], zf, 0, 0, 0);
#pragma unroll
    for (int kc = 1; kc < 8; ++kc)
#pragma unroll
      for (int t = 0; t < 4; ++t)
        acc[t] = __builtin_amdgcn_mfma_f32_16x16x32_f16(A[t][kc], bf[kc], acc[t], 0, 0, 0);

    // --- r,z finalize on the VALU while n MFMAs (below) fill the pipe ---
#define SEL8(x, y, out) do {                       \
      float p0 = s0 ? (x)[1] : (x)[0];             \
      float p1 = s0 ? (x)[3] : (x)[2];             \
      float p2 = s0 ? (y)[1] : (y)[0];             \
      float p3 = s0 ? (y)[3] : (y)[2];             \
      float q0 = s1 ? p1 : p0;                     \
      float q1 = s1 ? p3 : p2;                     \
      out = s2 ? q1 : q0;                          \
    } while (0)
    const bool s0 = (jsel & 1) != 0, s1 = (jsel & 2) != 0, s2 = (jsel & 4) != 0;
    float yr, yz;
    SEL8(acc[0], acc[1], yr);
    SEL8(acc[2], acc[3], yz);
    float rg = sigmoidf_fast(yr + br + xr0);
    float zg = sigmoidf_fast(yz + bz + xz0);

    // --- n tiles: 16 MFMAs, 2 chains (other wave + the VALU ops above
    //     keep the pipes fed) ---
    acc[4] = __builtin_amdgcn_mfma_f32_16x16x32_f16(A[4][0], bf[0], zf, 0, 0, 0);
    acc[5] = __builtin_amdgcn_mfma_f32_16x16x32_f16(A[5][0], bf[0], zf, 0, 0, 0);
#pragma unroll
    for (int kc = 1; kc < 8; ++kc) {
      acc[4] = __builtin_amdgcn_mfma_f32_16x16x32_f16(A[4][kc], bf[kc], acc[4], 0, 0, 0);
      acc[5] = __builtin_amdgcn_mfma_f32_16x16x32_f16(A[5][kc], bf[kc], acc[5], 0, 0, 0);
    }

    float yn;
    SEL8(acc[4], acc[5], yn);
#undef SEL8

    float ng = tanhf_fast(xn0 + rg * (yn + bnn));
    hreg = (1.0f - zg) * ng + zg * hreg;

    if (writer)
      hbuf[(s + 1) & 1][cm] = (_Float16)hreg;

    __syncthreads();
    xr0 = xr1; xz0 = xz1; xn0 = xn1;
  }

  // epilogue: final row (s = SEQ-1)
  if (writer)
    zout[(size_t)(SEQ - 1) * HID + cm] = hreg;
}

// ---------------------------------------------------------------------------
// Phase C: NCE loss + accuracy. One block per t, 4 waves = 4 timespans.
// Reads f32 z straight from d_out.
// ---------------------------------------------------------------------------
__global__ __launch_bounds__(256) void cpc_kernel(
    const float* __restrict__ x, const float* __restrict__ zf,
    const float* __restrict__ rn, float* __restrict__ accum)
{
  __shared__ float zsh[HID];
  __shared__ float wsum[4];
  __shared__ float nce_s[4], acc_s[4];
  const int tt = TSTART + blockIdx.x;
  const int i = threadIdx.x;
  const int wave = i >> 6, lane = i & 63;

  float zi = zf[(size_t)tt * HID + i];
  zsh[i] = zi;
  float p = zi * zi;
#pragma unroll
  for (int off = 32; off; off >>= 1) p += __shfl_xor(p, off, 64);
  if (lane == 0) wsum[wave] = p;
  __syncthreads();
  float zn = fmaxf(sqrtf(wsum[0] + wsum[1] + wsum[2] + wsum[3]), 1e-8f);

  float z0 = zsh[lane], z1 = zsh[lane + 64], z2 = zsh[lane + 128], z3 = zsh[lane + 192];
  const int base = tt + wave + 1;   // pos index for timespan (wave+1)

  float tot[10];
#pragma unroll
  for (int n = 0; n < 10; ++n) {
    int idx = base + (n > 0 ? (NEGD + n - 1) : 0);
    const float* xr = x + (size_t)idx * HID;
    float q = xr[lane] * z0 + xr[lane + 64] * z1 + xr[lane + 128] * z2 + xr[lane + 192] * z3;
#pragma unroll
    for (int off = 32; off; off >>= 1) q += __shfl_xor(q, off, 64);
    tot[n] = q / (rn[idx] * zn);
  }
  float m = tot[0];
#pragma unroll
  for (int n = 1; n < 10; ++n) m = fmaxf(m, tot[n]);
  float se = 0.f;
#pragma unroll
  for (int n = 0; n < 10; ++n) se += expf(tot[n] - m);
  float logp0 = (tot[0] - m) - logf(se);
  float accv = (tot[0] >= m) ? 1.0f : 0.0f;  // argmax==0 iff tot[0] is the max

  if (lane == 0) { nce_s[wave] = -logp0; acc_s[wave] = accv; }
  __syncthreads();
  if (i == 0) {
    atomicAdd(accum,     nce_s[0] + nce_s[1] + nce_s[2] + nce_s[3]);
    atomicAdd(accum + 1, acc_s[0] + acc_s[1] + acc_s[2] + acc_s[3]);
  }
}

__global__ void fin_kernel(const float* __restrict__ accum,
                           float* __restrict__ out)
{
  if (threadIdx.x == 0) {
    out[(size_t)SEQ * HID]     = accum[0] / DENOMF;   // nce
    out[(size_t)SEQ * HID + 1] = accum[1] / DENOMF;   // acc
  }
}

// ---------------------------------------------------------------------------
extern "C" void kernel_launch(void* const* d_in, const int* in_sizes, int n_in,
                              void* d_out, int out_size, void* d_ws, size_t ws_size,
                              hipStream_t stream)
{
  // Inputs are f32 (reference dtypes). Output f32: z [SEQ*HID] | nce | acc.
  const float* data = (const float*)d_in[0];
  const float* Wih  = (const float*)d_in[1];
  const float* Whh  = (const float*)d_in[2];
  const float* bih  = (const float*)d_in[3];
  const float* bhh  = (const float*)d_in[4];
  float* out = (float*)d_out;

  // ws layout: xw f32 [SEQ*768] 25.17MB | rn f32 [SEQ] | accum f32 [2]
  char* p = (char*)d_ws;
  float* xw    = (float*)p;  p += (size_t)SEQ * G3 * sizeof(float);
  float* rn    = (float*)p;  p += (size_t)SEQ * sizeof(float);
  float* accum = (float*)p;

  init_kernel<<<1, 64, 0, stream>>>(accum);
  xw_kernel<<<dim3(256, 3), 256, 0, stream>>>(data, Wih, bih, xw);
  rnorm_kernel<<<SEQ / 4, 256, 0, stream>>>(data, rn);
  gru_kernel<<<1, 512, 0, stream>>>(Whh, bhh, xw, out);
  cpc_kernel<<<TCNT, 256, 0, stream>>>(data, out, rn, accum);
  fin_kernel<<<1, 1, 0, stream>>>(accum, out);
}

// Round 15
// 7990.421 us; speedup vs baseline: 1.1702x; 1.1702x over previous
//
#include <hip/hip_runtime.h>

// Problem constants (from reference)
#define SEQ   8192
#define HID   256
#define G3    768      // 3*HID
#define TSTART 1024    // SEQ/8
#define NEGD  1365     // SEQ/6
#define TCNT  5791     // (SEQ - 10 - NEGD - 4 + 2) - TSTART
#define DENOMF 23164.0f // TCNT*4

typedef _Float16 half8_t __attribute__((ext_vector_type(8)));
typedef float    f32x4  __attribute__((ext_vector_type(4)));

__device__ __forceinline__ float sigmoidf_fast(float x) {
  return 1.0f / (1.0f + __expf(-x));
}
// tanh via sigmoid form: safe at both extremes (exp under/overflow -> +-1)
__device__ __forceinline__ float tanhf_fast(float x) {
  return 2.0f / (1.0f + __expf(-2.0f * x)) - 1.0f;
}

// ---------------------------------------------------------------------------
// init: zero the loss accumulators (ws is poisoned 0xAA every call)
// ---------------------------------------------------------------------------
__global__ void init_kernel(float* accum) {
  if (threadIdx.x < 2) accum[threadIdx.x] = 0.0f;
}

// ---------------------------------------------------------------------------
// Phase A: xW = data @ Wih^T + bih -> f32 [SEQ][768]. All f32.
// grid (256, 3), block 256. Thread owns output col o; 32-row x-tile in LDS.
// ---------------------------------------------------------------------------
__global__ __launch_bounds__(256) void xw_kernel(
    const float* __restrict__ data, const float* __restrict__ Wih,
    const float* __restrict__ bih, float* __restrict__ xw)
{
  __shared__ float4 xs4[32 * 64];   // 32 rows x 256 f32 = 32 KB
  const int o  = blockIdx.y * 256 + threadIdx.x;
  const int m0 = blockIdx.x * 32;

  float* xsf = (float*)xs4;
  for (int r = 0; r < 32; ++r)
    xsf[r * 256 + threadIdx.x] = data[(size_t)(m0 + r) * 256 + threadIdx.x];
  __syncthreads();

  const float b = bih[o];
  float acc[32];
#pragma unroll
  for (int r = 0; r < 32; ++r) acc[r] = b;

  const float4* wrow = (const float4*)(Wih + (size_t)o * 256);
  for (int kc = 0; kc < 4; ++kc) {
    float4 w[16];
#pragma unroll
    for (int j = 0; j < 16; ++j) w[j] = wrow[kc * 16 + j];
#pragma unroll
    for (int r = 0; r < 32; ++r) {
      const float4* xr = xs4 + r * 64 + kc * 16;
      float a0 = 0.f, a1 = 0.f, a2 = 0.f, a3 = 0.f;
#pragma unroll
      for (int j = 0; j < 4; ++j) {
        float4 x0 = xr[4 * j + 0], x1 = xr[4 * j + 1];
        float4 x2 = xr[4 * j + 2], x3 = xr[4 * j + 3];
        float4 w0 = w[4 * j + 0], w1 = w[4 * j + 1];
        float4 w2 = w[4 * j + 2], w3 = w[4 * j + 3];
        a0 = fmaf(w0.x, x0.x, fmaf(w0.y, x0.y, fmaf(w0.z, x0.z, fmaf(w0.w, x0.w, a0))));
        a1 = fmaf(w1.x, x1.x, fmaf(w1.y, x1.y, fmaf(w1.z, x1.z, fmaf(w1.w, x1.w, a1))));
        a2 = fmaf(w2.x, x2.x, fmaf(w2.y, x2.y, fmaf(w2.z, x2.z, fmaf(w2.w, x2.w, a2))));
        a3 = fmaf(w3.x, x3.x, fmaf(w3.y, x3.y, fmaf(w3.z, x3.z, fmaf(w3.w, x3.w, a3))));
      }
      acc[r] += (a0 + a1) + (a2 + a3);
    }
  }
  for (int r = 0; r < 32; ++r)
    xw[(size_t)(m0 + r) * G3 + o] = acc[r];
}

// ---------------------------------------------------------------------------
// data row norms: one wave per row (f32 data)
// ---------------------------------------------------------------------------
__global__ __launch_bounds__(256) void rnorm_kernel(
    const float* __restrict__ data, float* __restrict__ rn)
{
  int wave = threadIdx.x >> 6, lane = threadIdx.x & 63;
  int row = blockIdx.x * 4 + wave;
  const float* xr = data + (size_t)row * HID;
  float a = xr[lane], b = xr[lane + 64], c = xr[lane + 128], d = xr[lane + 192];
  float s = a * a + b * b + c * c + d * d;
#pragma unroll
  for (int off = 32; off; off >>= 1) s += __shfl_xor(s, off, 64);
  if (lane == 0) rn[row] = fmaxf(sqrtf(s), 1e-8f);
}

// ---------------------------------------------------------------------------
// Phase B: sequential GRU scan via MFMA matvec. ONE block, 512 threads
// (8 waves, 2/SIMD). FINAL configuration = round-10 verbatim (7613us gru,
// 7971us total, passed) -- the measured optimum of this structure.
//
// Why this is the plateau (A/B evidence across rounds 4-14):
//  * MFMA pipe busy is invariant at ~1526 cyc/SIMD/step = the 96-MFMA
//    matvec issue floor (0.268*2231 = 0.248*2403 = 0.226*2638).
//  * Store placement: before-barrier 2231 / loop-top 2403-2406 /
//    mid-body 2638 -- the compiler's schedule with the store just before
//    __syncthreads is optimal; the vmcnt(0) drain is effectively free.
//  * 16 waves (r9): +VALU overhead scales with threads -> 2638. fdot2
//    paths (r3/5/7): ~3x over VALU model (AGPR pathologies). fp8 K=128
//    (r8): absmax 0.70 fail on the 8192-step recurrence. Raw asm barrier
//    (r12): neutral vs __syncthreads (r13 isolated).
// The ~700-cyc serial residue is the true critical path (bf ds_read
// latency + MFMA->VALU latency + SEL/sigmoid/tanh/ds_write + barrier),
// partially overlapped across the 2 waves/SIMD.
//
// Mappings (verified round 4): A-frag row = lane&15, k = kc*32+(lane>>4)*8+j.
// B = h broadcast into all 16 columns -> every C column equals y.
// C: col=lane&15, row=(lane>>4)*4+reg. Lane (g, jsel=lane&7) finalizes
// column cm = w*32+(jsel>>2)*16+g*4+(jsel&3); copy r16<8 publishes.
// ONE barrier per step; h double-buffered f16 in LDS.
// ---------------------------------------------------------------------------
__global__ __launch_bounds__(512, 2) void gru_kernel(
    const float* __restrict__ Whh, const float* __restrict__ bhh,
    const float* __restrict__ xw, float* __restrict__ zout)
{
  __shared__ __align__(16) _Float16 hbuf[2][HID];   // double-buffered h
  const int i    = threadIdx.x;
  const int w    = i >> 6;
  const int lane = i & 63;
  const int g    = lane >> 4;          // C-rows g*4..g*4+3; B k-sub g*8..+8
  const int r16  = lane & 15;          // A-fragment row within a 16-row tile
  const int jsel = lane & 7;           // (t2,reg) this lane finalizes
  const int cm   = w * 32 + (jsel >> 2) * 16 + g * 4 + (jsel & 3);
  const bool writer = r16 < 8;         // one finalizer copy publishes

  // --- resident A-fragments: [G*2+t2][kc], 192 AGPR-backed regs ---
  half8_t A[6][8];
#pragma unroll
  for (int G = 0; G < 3; ++G)
#pragma unroll
    for (int t2 = 0; t2 < 2; ++t2) {
      const int row = G * 256 + w * 32 + t2 * 16 + r16;
      const float* wp = Whh + (size_t)row * 256 + g * 8;
#pragma unroll
      for (int kc = 0; kc < 8; ++kc) {
        const float4* w4 = (const float4*)(wp + kc * 32);
        float4 u = w4[0], v = w4[1];
        half8_t f;
        f[0] = (_Float16)u.x; f[1] = (_Float16)u.y;
        f[2] = (_Float16)u.z; f[3] = (_Float16)u.w;
        f[4] = (_Float16)v.x; f[5] = (_Float16)v.y;
        f[6] = (_Float16)v.z; f[7] = (_Float16)v.w;
        A[G * 2 + t2][kc] = f;
      }
    }

  const float br  = bhh[cm];
  const float bz  = bhh[256 + cm];
  const float bnn = bhh[512 + cm];

  if (i < HID) hbuf[0][i] = (_Float16)0.0f;
  __syncthreads();

  float hreg = 0.0f;   // h[cm], tracked by both r16-parity copies
  const float* xwp = xw;       // row-s pointer, += G3 per step
  float*       zp  = zout;     // row-s output pointer, += HID per step
  float xr0 = xwp[cm], xz0 = xwp[256 + cm], xn0 = xwp[512 + cm];

  const f32x4 zf = {0.f, 0.f, 0.f, 0.f};

  for (int s = 0; s < SEQ; ++s) {
    // next step's xW prefetch, unconditional (last iter reads into the rn
    // region: in-bounds garbage, never used)
    xwp += G3;
    float xr1 = xwp[cm], xz1 = xwp[256 + cm], xn1 = xwp[512 + cm];

    const _Float16* hc = hbuf[s & 1];

    // --- all 8 B-frags upfront (compile-time indexed; reads overlap) ---
    half8_t bf[8];
#pragma unroll
    for (int kc = 0; kc < 8; ++kc)
      bf[kc] = *(const half8_t*)(hc + kc * 32 + g * 8);

    // --- r,z tiles first: 32 MFMAs, 4 independent chains ---
    f32x4 acc[6];
#pragma unroll
    for (int t = 0; t < 4; ++t)
      acc[t] = __builtin_amdgcn_mfma_f32_16x16x32_f16(A[t][0], bf[0], zf, 0, 0, 0);
#pragma unroll
    for (int kc = 1; kc < 8; ++kc)
#pragma unroll
      for (int t = 0; t < 4; ++t)
        acc[t] = __builtin_amdgcn_mfma_f32_16x16x32_f16(A[t][kc], bf[kc], acc[t], 0, 0, 0);

    // --- r,z finalize on the VALU while n MFMAs (below) fill the pipe ---
#define SEL8(x, y, out) do {                       \
      float p0 = s0 ? (x)[1] : (x)[0];             \
      float p1 = s0 ? (x)[3] : (x)[2];             \
      float p2 = s0 ? (y)[1] : (y)[0];             \
      float p3 = s0 ? (y)[3] : (y)[2];             \
      float q0 = s1 ? p1 : p0;                     \
      float q1 = s1 ? p3 : p2;                     \
      out = s2 ? q1 : q0;                          \
    } while (0)
    const bool s0 = (jsel & 1) != 0, s1 = (jsel & 2) != 0, s2 = (jsel & 4) != 0;
    float yr, yz;
    SEL8(acc[0], acc[1], yr);
    SEL8(acc[2], acc[3], yz);
    float rg = sigmoidf_fast(yr + br + xr0);
    float zg = sigmoidf_fast(yz + bz + xz0);

    // --- n tiles: 16 MFMAs, 2 chains (other wave + the VALU ops above
    //     keep the pipes fed) ---
    acc[4] = __builtin_amdgcn_mfma_f32_16x16x32_f16(A[4][0], bf[0], zf, 0, 0, 0);
    acc[5] = __builtin_amdgcn_mfma_f32_16x16x32_f16(A[5][0], bf[0], zf, 0, 0, 0);
#pragma unroll
    for (int kc = 1; kc < 8; ++kc) {
      acc[4] = __builtin_amdgcn_mfma_f32_16x16x32_f16(A[4][kc], bf[kc], acc[4], 0, 0, 0);
      acc[5] = __builtin_amdgcn_mfma_f32_16x16x32_f16(A[5][kc], bf[kc], acc[5], 0, 0, 0);
    }

    float yn;
    SEL8(acc[4], acc[5], yn);
#undef SEL8

    float ng = tanhf_fast(xn0 + rg * (yn + bnn));
    hreg = (1.0f - zg) * ng + zg * hreg;

    if (writer) {
      hbuf[(s + 1) & 1][cm] = (_Float16)hreg;
      zp[cm] = hreg;
    }
    __syncthreads();
    zp += HID;
    xr0 = xr1; xz0 = xz1; xn0 = xn1;
  }
}

// ---------------------------------------------------------------------------
// Phase C: NCE loss + accuracy. One block per t, 4 waves = 4 timespans.
// Reads f32 z straight from d_out.
// ---------------------------------------------------------------------------
__global__ __launch_bounds__(256) void cpc_kernel(
    const float* __restrict__ x, const float* __restrict__ zf,
    const float* __restrict__ rn, float* __restrict__ accum)
{
  __shared__ float zsh[HID];
  __shared__ float wsum[4];
  __shared__ float nce_s[4], acc_s[4];
  const int tt = TSTART + blockIdx.x;
  const int i = threadIdx.x;
  const int wave = i >> 6, lane = i & 63;

  float zi = zf[(size_t)tt * HID + i];
  zsh[i] = zi;
  float p = zi * zi;
#pragma unroll
  for (int off = 32; off; off >>= 1) p += __shfl_xor(p, off, 64);
  if (lane == 0) wsum[wave] = p;
  __syncthreads();
  float zn = fmaxf(sqrtf(wsum[0] + wsum[1] + wsum[2] + wsum[3]), 1e-8f);

  float z0 = zsh[lane], z1 = zsh[lane + 64], z2 = zsh[lane + 128], z3 = zsh[lane + 192];
  const int base = tt + wave + 1;   // pos index for timespan (wave+1)

  float tot[10];
#pragma unroll
  for (int n = 0; n < 10; ++n) {
    int idx = base + (n > 0 ? (NEGD + n - 1) : 0);
    const float* xr = x + (size_t)idx * HID;
    float q = xr[lane] * z0 + xr[lane + 64] * z1 + xr[lane + 128] * z2 + xr[lane + 192] * z3;
#pragma unroll
    for (int off = 32; off; off >>= 1) q += __shfl_xor(q, off, 64);
    tot[n] = q / (rn[idx] * zn);
  }
  float m = tot[0];
#pragma unroll
  for (int n = 1; n < 10; ++n) m = fmaxf(m, tot[n]);
  float se = 0.f;
#pragma unroll
  for (int n = 0; n < 10; ++n) se += expf(tot[n] - m);
  float logp0 = (tot[0] - m) - logf(se);
  float accv = (tot[0] >= m) ? 1.0f : 0.0f;  // argmax==0 iff tot[0] is the max

  if (lane == 0) { nce_s[wave] = -logp0; acc_s[wave] = accv; }
  __syncthreads();
  if (i == 0) {
    atomicAdd(accum,     nce_s[0] + nce_s[1] + nce_s[2] + nce_s[3]);
    atomicAdd(accum + 1, acc_s[0] + acc_s[1] + acc_s[2] + acc_s[3]);
  }
}

__global__ void fin_kernel(const float* __restrict__ accum,
                           float* __restrict__ out)
{
  if (threadIdx.x == 0) {
    out[(size_t)SEQ * HID]     = accum[0] / DENOMF;   // nce
    out[(size_t)SEQ * HID + 1] = accum[1] / DENOMF;   // acc
  }
}

// ---------------------------------------------------------------------------
extern "C" void kernel_launch(void* const* d_in, const int* in_sizes, int n_in,
                              void* d_out, int out_size, void* d_ws, size_t ws_size,
                              hipStream_t stream)
{
  // Inputs are f32 (reference dtypes). Output f32: z [SEQ*HID] | nce | acc.
  const float* data = (const float*)d_in[0];
  const float* Wih  = (const float*)d_in[1];
  const float* Whh  = (const float*)d_in[2];
  const float* bih  = (const float*)d_in[3];
  const float* bhh  = (const float*)d_in[4];
  float* out = (float*)d_out;

  // ws layout: xw f32 [SEQ*768] 25.17MB | rn f32 [SEQ] | accum f32 [2]
  char* p = (char*)d_ws;
  float* xw    = (float*)p;  p += (size_t)SEQ * G3 * sizeof(float);
  float* rn    = (float*)p;  p += (size_t)SEQ * sizeof(float);
  float* accum = (float*)p;

  init_kernel<<<1, 64, 0, stream>>>(accum);
  xw_kernel<<<dim3(256, 3), 256, 0, stream>>>(data, Wih, bih, xw);
  rnorm_kernel<<<SEQ / 4, 256, 0, stream>>>(data, rn);
  gru_kernel<<<1, 512, 0, stream>>>(Whh, bhh, xw, out);
  cpc_kernel<<<TCNT, 256, 0, stream>>>(data, out, rn, accum);
  fin_kernel<<<1, 1, 0, stream>>>(accum, out);
}